// Round 3
// baseline (396.721 us; speedup 1.0000x reference)
//
#include <hip/hip_runtime.h>

// RNN: o_t = tanh(relu([x_t, o_{t-1}] @ W1[t] + b1[t]) @ W2[t] + b2[t]), T=30.
// Round-4 design (packed math + time-chunked tile):
//  - Round-3 post-mortem: occupancy 47%, VALUBusy 88% -> VALU-ISSUE-bound.
//    Busy-cycle comparison: M=2 pk_fma stream = 61us pipe time, M=1 scalar
//    stream = 96us. v_pk_fma_f32 IS ~double-throughput per issue slot
//    (5 VALU ops per j for TWO elements vs 5 for one). Restore M=2 packed
//    math; keep/exceed round-3 occupancy by shrinking the tile.
//  - Time-chunked LDS tile: recurrence carries o in REGISTERS across chunks;
//    LDS is only the I/O transposer. 3 chunks x 10 steps: tile = 10*512*4 =
//    20480 B exactly -> 8 blocks/CU = 32 waves/CU = 100% occupancy, entire
//    2048-block grid resident. Chunk granule 40 B/elem keeps global I/O as
//    aligned float2 (e*120 + c*40 is 8B-aligned).
//  - ROW=512 unpadded would make the scatter an 8-way bank conflict (lanes
//    sharing e, differing tt -> bank e%32). XOR-swizzle column with e ^ 2*tt:
//    preserves bit0 (b64 compute reads stay 8B-aligned, 2-way = free) and
//    spreads the scatter to <=2-way (free).
//  - Weights: float4 {w1x,w1h,b1,w2}[t][j] (+b2 slot 20), wave-uniform ->
//    s_load_dwordx4 on the scalar pipe.
// __launch_bounds__(256,8) caps VGPR at 64 (round 3 used 44; M=2 adds ~6).

#define TS   30
#define CH   10              // timesteps per chunk
#define NCH  3
#define THR  256
#define EPB  512             // elements per block (M=2 per thread)
#define ROW  512             // tile row stride in dwords (swizzled, no pad)

typedef float f2 __attribute__((ext_vector_type(2)));

__device__ __forceinline__ float fast_tanh(float y) {
    // tanh(y) = 1 - 2/(exp(2y)+1); correct saturation at +/-inf.
    float e = __expf(2.0f * y);
    return 1.0f - 2.0f * __builtin_amdgcn_rcpf(e + 1.0f);
}

__global__ __launch_bounds__(256) void repack_w(
        const float* __restrict__ W1, const float* __restrict__ b1,
        const float* __restrict__ W2, const float* __restrict__ b2,
        float4* __restrict__ wp) {
    for (int i = threadIdx.x; i < TS * 21; i += 256) {
        const int t = i / 21;
        const int j = i - t * 21;
        float4 v;
        if (j < 20) v = make_float4(W1[t * 40 + j], W1[t * 40 + 20 + j],
                                    b1[t * 20 + j], W2[t * 20 + j]);
        else        v = make_float4(b2[t], 0.f, 0.f, 0.f);
        wp[i] = v;
    }
}

__global__ __launch_bounds__(256, 8) void rnn4(
        const float* __restrict__ x,
        const float4* __restrict__ wp,
        float* __restrict__ out) {
    __shared__ float tile[CH * ROW];                 // 20480 B -> 8 blocks/CU
    const int tid = threadIdx.x;
    const size_t gb2 = (size_t)blockIdx.x * (EPB * TS / 2);  // float2 units
    const float2* xg = reinterpret_cast<const float2*>(x);
    float2* og = reinterpret_cast<float2*>(out);

    const int e0 = 2 * tid;                          // this thread's elements
    f2 o = {0.f, 0.f};

#pragma unroll 1
    for (int c = 0; c < NCH; ++c) {
        // ---- load chunk c: coalesced float2, transpose-scatter into tile ----
#pragma unroll
        for (int i = 0; i < CH; ++i) {
            const unsigned p = (unsigned)(i * THR + tid);     // [0, 2560)
            const unsigned e = (p * 52429u) >> 18;            // exact p/5
            const unsigned q = p - e * 5u;                    // [0,5)
            const float2 v = xg[gb2 + e * 15u + (unsigned)c * 5u + q];
            const unsigned tt0 = 2u * q;
            tile[tt0 * ROW + (e ^ (2u * tt0))]             = v.x;
            tile[(tt0 + 1u) * ROW + (e ^ (2u * tt0 + 2u))] = v.y;
        }
        __syncthreads();

        // ---- recurrence: CH steps, packed M=2, weights via s_load ----
#pragma unroll 1
        for (int tt = 0; tt < CH; ++tt) {
            const int t = c * CH + tt;
            const float4* wr = wp + t * 21;          // wave-uniform -> s_load
            const unsigned idx = (unsigned)tt * ROW +
                                 ((unsigned)e0 ^ (2u * (unsigned)tt));
            const f2 xv = *reinterpret_cast<const f2*>(&tile[idx]);
            const float bb = wr[20].x;
            f2 acc = {bb, bb};
#pragma unroll
            for (int j = 0; j < 20; ++j) {
                const float4 w = wr[j];              // s_load_dwordx4
                f2 h = xv * w.x + o * w.y + w.z;     // 2x v_pk_fma_f32 (+mov)
                h.x = __builtin_fmaxf(h.x, 0.f);
                h.y = __builtin_fmaxf(h.y, 0.f);     // v_pk_max_f32
                acc += h * w.w;                      // v_pk_fma_f32
            }
            o.x = fast_tanh(acc.x);
            o.y = fast_tanh(acc.y);
            *reinterpret_cast<f2*>(&tile[idx]) = o;  // in-place: x -> o
        }
        __syncthreads();

        // ---- store chunk c: gather from tile, coalesced float2 ----
#pragma unroll
        for (int i = 0; i < CH; ++i) {
            const unsigned p = (unsigned)(i * THR + tid);
            const unsigned e = (p * 52429u) >> 18;
            const unsigned q = p - e * 5u;
            const unsigned tt0 = 2u * q;
            float2 v;
            v.x = tile[tt0 * ROW + (e ^ (2u * tt0))];
            v.y = tile[(tt0 + 1u) * ROW + (e ^ (2u * tt0 + 2u))];
            og[gb2 + e * 15u + (unsigned)c * 5u + q] = v;
        }
        __syncthreads();                             // tile reused next chunk
    }
}

extern "C" void kernel_launch(void* const* d_in, const int* in_sizes, int n_in,
                              void* d_out, int out_size, void* d_ws, size_t ws_size,
                              hipStream_t stream) {
    const float* x  = (const float*)d_in[0];
    const float* W1 = (const float*)d_in[1];
    const float* b1 = (const float*)d_in[2];
    const float* W2 = (const float*)d_in[3];
    const float* b2 = (const float*)d_in[4];
    float* out = (float*)d_out;
    float4* wp = (float4*)d_ws;                      // 30*21*16 = 10080 B

    repack_w<<<1, 256, 0, stream>>>(W1, b1, W2, b2, wp);

    const int B = 1048576;
    const int grid = B / EPB;                        // 2048 blocks
    rnn4<<<grid, 256, 0, stream>>>(x, wp, out);
}

// Round 4
// 360.041 us; speedup vs baseline: 1.1019x; 1.1019x over previous
//
#include <hip/hip_runtime.h>

// RNN: o_t = tanh(relu([x_t, o_{t-1}] @ W1[t] + b1[t]) @ W2[t] + b2[t]), T=30.
// Round-5 design (all-register, zero-LDS):
//  - Round-4 post-mortem: time-chunked LDS tile broke cache-line granularity.
//    Each chunk read 40B runs of every 120B row -> FETCH 61.5->298MB (~input
//    x2.4) and partial-line RMW writes -> WRITE 122.9->325MB. Memory-bound at
//    VALUBusy 26%. Lesson: every phase must touch full 120B rows.
//  - M=2 fix: thread g owns elements 2g,2g+1 -> its data is ONE contiguous
//    240B region = exactly 15 aligned float4s. Load all 30 timesteps of both
//    elements into 60 VGPRs (statically indexed -> SROA), run the recurrence
//    in-place (x_t reg becomes o_t reg), store 15 float4s back. Every HBM
//    line fetched once / written once, fully used. No LDS, no barriers, no
//    transpose index math.
//  - Packed math (v_pk_fma_f32): weights repacked with each scalar DUPLICATED
//    into an 8B pair -> s_load gives SGPR pairs directly usable as pk-op
//    broadcast operands (1 SGPR-pair read per VALU op = legal). Layout per
//    (t,j): 4 f2 pairs {w1x,w1h,b1,w2}; slot j=20 carries {b2,b2}.
//    Per j: 4 pk ops for 2 elements (vs 5 scalar ops per 1 element in r3).
//  - Arithmetic identical to round-2/3 formula (same absmax 0.00390625).
//  - Occupancy: ~85-100 VGPR -> 4 waves/SIMD (16/CU, 50%). Fine: no barriers,
//    j-loop is pure issue-bound pk-FMA with 4-deep dependent chain << issue.
// Floors: VALU ~34us, memory 252MB/6.3TBps ~40us -> target ~55us dispatch.

#define TS  30
#define HID 20
#define THR 256

typedef float f2 __attribute__((ext_vector_type(2)));

__device__ __forceinline__ float fast_tanh(float y) {
    // tanh(y) = 1 - 2/(exp(2y)+1); correct saturation at +/-inf.
    float e = __expf(2.0f * y);
    return 1.0f - 2.0f * __builtin_amdgcn_rcpf(e + 1.0f);
}

// Repack weights into duplicated pairs: wp2[(t*21+j)*4 + {0,1,2,3}] =
// {W1x,W1x},{W1h,W1h},{b1,b1},{W2,W2}; slot j=20: {b2,b2},{0,0},{0,0},{0,0}.
__global__ __launch_bounds__(256) void repack_w(
        const float* __restrict__ W1, const float* __restrict__ b1,
        const float* __restrict__ W2, const float* __restrict__ b2,
        f2* __restrict__ wp2) {
    for (int i = threadIdx.x; i < TS * 21; i += 256) {
        const int t = i / 21;
        const int j = i - t * 21;
        f2 a, b, c, d;
        if (j < HID) {
            const float wx = W1[t * 40 + j];
            const float wh = W1[t * 40 + 20 + j];
            const float bb = b1[t * 20 + j];
            const float w2 = W2[t * 20 + j];
            a = (f2){wx, wx}; b = (f2){wh, wh};
            c = (f2){bb, bb}; d = (f2){w2, w2};
        } else {
            const float bb2 = b2[t];
            a = (f2){bb2, bb2}; b = (f2){0.f, 0.f};
            c = (f2){0.f, 0.f}; d = (f2){0.f, 0.f};
        }
        f2* o = wp2 + (size_t)i * 4;
        o[0] = a; o[1] = b; o[2] = c; o[3] = d;
    }
}

__global__ __launch_bounds__(256, 4) void rnn5(
        const float* __restrict__ x,
        const f2* __restrict__ wp2,
        float* __restrict__ out) {
    const int tid = threadIdx.x;
    // Thread g owns elements 2g, 2g+1: floats [60g, 60g+60) = float4s
    // [15g, 15g+15), base byte 240g -> 16B-aligned.
    const size_t base4 = ((size_t)blockIdx.x * THR + tid) * 15u;
    const float4* xg = reinterpret_cast<const float4*>(x);

    float rf[60];                                    // SROA -> 60 VGPRs
#pragma unroll
    for (int i = 0; i < 15; ++i) {
        const float4 v = xg[base4 + i];
        rf[4 * i + 0] = v.x; rf[4 * i + 1] = v.y;
        rf[4 * i + 2] = v.z; rf[4 * i + 3] = v.w;
    }
    // rf[t] = x[e0][t], rf[30+t] = x[e1][t]; overwritten with o in place.

    f2 o = {0.f, 0.f};
#pragma unroll
    for (int t = 0; t < TS; ++t) {
        const f2* wr = wp2 + t * 84;                 // wave-uniform -> s_load
        const f2 xv = {rf[t], rf[30 + t]};
        f2 acc = wr[80];                             // {b2[t], b2[t]}
#pragma unroll
        for (int j = 0; j < HID; ++j) {
            const f2 wx = wr[4 * j + 0];             // s-pair broadcast
            const f2 wh = wr[4 * j + 1];
            const f2 bb = wr[4 * j + 2];
            const f2 w2 = wr[4 * j + 3];
            f2 h = xv * wx + o * wh + bb;            // v_pk_fma_f32 x2
            h.x = __builtin_fmaxf(h.x, 0.f);
            h.y = __builtin_fmaxf(h.y, 0.f);         // v_pk_max_f32
            acc += h * w2;                           // v_pk_fma_f32
        }
        o.x = fast_tanh(acc.x);
        o.y = fast_tanh(acc.y);
        rf[t] = o.x; rf[30 + t] = o.y;               // in place: x -> o
    }

    float4* og = reinterpret_cast<float4*>(out);
#pragma unroll
    for (int i = 0; i < 15; ++i) {
        const float4 v = make_float4(rf[4 * i + 0], rf[4 * i + 1],
                                     rf[4 * i + 2], rf[4 * i + 3]);
        og[base4 + i] = v;
    }
}

extern "C" void kernel_launch(void* const* d_in, const int* in_sizes, int n_in,
                              void* d_out, int out_size, void* d_ws, size_t ws_size,
                              hipStream_t stream) {
    const float* x  = (const float*)d_in[0];
    const float* W1 = (const float*)d_in[1];
    const float* b1 = (const float*)d_in[2];
    const float* W2 = (const float*)d_in[3];
    const float* b2 = (const float*)d_in[4];
    float* out = (float*)d_out;
    f2* wp2 = (f2*)d_ws;                             // 30*21*4*8 = 20160 B

    repack_w<<<1, 256, 0, stream>>>(W1, b1, W2, b2, wp2);

    const int B = 1048576;
    const int grid = B / (2 * THR);                  // 2048 blocks
    rnn5<<<grid, THR, 0, stream>>>(x, wp2, out);
}

// Round 5
// 357.621 us; speedup vs baseline: 1.1093x; 1.0068x over previous
//
#include <hip/hip_runtime.h>

// RNN: o_t = tanh(relu([x_t, o_{t-1}] @ W1[t] + b1[t]) @ W2[t] + b2[t]), T=30.
// Round-6 design (named-register recurrence + half-phased LDS transpose):
//  - r5 post-mortem: VGPR_Count=44 proved rf[60] was never promoted (SROA vs
//    unroll ordering, rule-#20 trap) -> 500MB scratch tax, memory-bound 24%
//    VALUBusy. Fix: time series in 30 NAMED f2 variables (r0..r29) via
//    macros; no arrays, no address-taken -> promotion guaranteed.
//  - r4 lesson: every global phase touches full 120B rows -> keep r3's
//    proven LDS-transpose staging (clean 61/123MB traffic).
//  - r2/r3 lesson: packed M=2 (v_pk_fma_f32) costs ~0.64x the pipe cycles
//    of scalar M=1. Weights repacked as DUPLICATED 8B pairs (r5 layout):
//    s_load yields SGPR pairs directly usable as pk broadcast operands.
//  - Tile stays 256 elems (30x258x4B = 30960B -> 5 blocks/CU = 20 waves/CU)
//    while the block owns 512 elems: input staged in TWO half-phases; after
//    each, the owning half of the threads copies its rows LDS->regs. Output
//    mirrors. Recurrence itself: zero LDS, zero barriers, pure pk-FMA with
//    wave-uniform s_load weights.
//  - ROW=258 (even): b64 reg-copy reads/writes stay 8B-aligned; scatter and
//    copy conflicts <=4-way on few ops (r2/r3 showed this is ~1us class).
// Floors: VALU pipe ~55us (0.55x r3's 96), memory 252MB ~40us -> target ~65us.

#define TS  30
#define HID 20
#define THR 256
#define EPB 512              // elements per block (M=2 per thread)
#define ROW 258              // tile row stride in floats (even: b64-aligned)
#define HLF 7680             // floats per half (256 elems * 30)

typedef float f2 __attribute__((ext_vector_type(2)));

__device__ __forceinline__ float fast_tanh(float y) {
    // tanh(y) = 1 - 2/(exp(2y)+1); correct saturation at +/-inf.
    float e = __expf(2.0f * y);
    return 1.0f - 2.0f * __builtin_amdgcn_rcpf(e + 1.0f);
}

// wp2[(t*21+j)*4 + {0,1,2,3}] = {W1x,W1x},{W1h,W1h},{b1,b1},{W2,W2};
// slot j=20: {b2,b2},0,0,0.
__global__ __launch_bounds__(256) void repack_w(
        const float* __restrict__ W1, const float* __restrict__ b1,
        const float* __restrict__ W2, const float* __restrict__ b2,
        f2* __restrict__ wp2) {
    for (int i = threadIdx.x; i < TS * 21; i += 256) {
        const int t = i / 21;
        const int j = i - t * 21;
        f2 a, b, c, d;
        if (j < HID) {
            const float wx = W1[t * 40 + j];
            const float wh = W1[t * 40 + 20 + j];
            const float bb = b1[t * 20 + j];
            const float w2 = W2[t * 20 + j];
            a = (f2){wx, wx}; b = (f2){wh, wh};
            c = (f2){bb, bb}; d = (f2){w2, w2};
        } else {
            const float bb2 = b2[t];
            a = (f2){bb2, bb2}; b = (f2){0.f, 0.f};
            c = (f2){0.f, 0.f}; d = (f2){0.f, 0.f};
        }
        f2* o = wp2 + (size_t)i * 4;
        o[0] = a; o[1] = b; o[2] = c; o[3] = d;
    }
}

__global__ __launch_bounds__(256, 5) void rnn6(
        const float* __restrict__ x,
        const f2* __restrict__ wp2,
        float* __restrict__ out) {
    __shared__ float tile[TS * ROW];                 // 30960 B -> 5 blocks/CU
    const int tid = threadIdx.x;
    const size_t gbase = (size_t)blockIdx.x * (EPB * TS);
    const unsigned el = 2u * (unsigned)(tid & 127);  // element col in tile

    // 30 timesteps x 2 elements, all in named registers.
    f2 r0, r1, r2, r3, r4, r5, r6, r7, r8, r9, r10, r11, r12, r13, r14,
       r15, r16, r17, r18, r19, r20, r21, r22, r23, r24, r25, r26, r27,
       r28, r29;

#define STAGE_IN(h)                                                         \
    {                                                                       \
        const float2* xg =                                                  \
            reinterpret_cast<const float2*>(x + gbase + (h) * HLF);         \
        _Pragma("unroll")                                                   \
        for (int i = 0; i < 15; ++i) {                                      \
            const float2 v = xg[i * THR + tid];                             \
            const unsigned f0 = (unsigned)(i * THR + tid) * 2u;             \
            const unsigned e0 = (f0 * 34953u) >> 20;  /* exact f/30 */      \
            const unsigned t0 = f0 - e0 * 30u;                              \
            tile[t0 * ROW + e0] = v.x;                                      \
            const unsigned f1 = f0 + 1u;                                    \
            const unsigned e1 = (f1 * 34953u) >> 20;                        \
            const unsigned t1 = f1 - e1 * 30u;                              \
            tile[t1 * ROW + e1] = v.y;                                      \
        }                                                                   \
    }

#define STAGE_OUT(h)                                                        \
    {                                                                       \
        float2* og = reinterpret_cast<float2*>(out + gbase + (h) * HLF);    \
        _Pragma("unroll")                                                   \
        for (int i = 0; i < 15; ++i) {                                      \
            const unsigned f0 = (unsigned)(i * THR + tid) * 2u;             \
            const unsigned e0 = (f0 * 34953u) >> 20;                        \
            const unsigned t0 = f0 - e0 * 30u;                              \
            const unsigned f1 = f0 + 1u;                                    \
            const unsigned e1 = (f1 * 34953u) >> 20;                        \
            const unsigned t1 = f1 - e1 * 30u;                              \
            float2 v;                                                       \
            v.x = tile[t0 * ROW + e0];                                      \
            v.y = tile[t1 * ROW + e1];                                      \
            og[i * THR + tid] = v;                                          \
        }                                                                   \
    }

#define LOADR(T, R) R = *reinterpret_cast<const f2*>(&tile[(T) * ROW + el]);
#define SAVER(T, R) *reinterpret_cast<f2*>(&tile[(T) * ROW + el]) = R;

#define ALLR(OP) OP(0, r0) OP(1, r1) OP(2, r2) OP(3, r3) OP(4, r4)          \
    OP(5, r5) OP(6, r6) OP(7, r7) OP(8, r8) OP(9, r9) OP(10, r10)           \
    OP(11, r11) OP(12, r12) OP(13, r13) OP(14, r14) OP(15, r15)             \
    OP(16, r16) OP(17, r17) OP(18, r18) OP(19, r19) OP(20, r20)             \
    OP(21, r21) OP(22, r22) OP(23, r23) OP(24, r24) OP(25, r25)             \
    OP(26, r26) OP(27, r27) OP(28, r28) OP(29, r29)

    // ---- input: two half-phases (full 120B rows per phase, r4 lesson) ----
    STAGE_IN(0);
    __syncthreads();
    if (tid < 128) { ALLR(LOADR) }
    __syncthreads();
    STAGE_IN(1);
    __syncthreads();
    if (tid >= 128) { ALLR(LOADR) }

    // ---- recurrence: pure registers + wave-uniform s_load weights ----
    f2 o = {0.f, 0.f};
#define STEP(T, R)                                                          \
    {                                                                       \
        const f2* wr = wp2 + (T) * 84;               /* -> s_load */        \
        const f2 xv = R;                                                    \
        f2 acc = wr[80];                             /* {b2,b2} */          \
        _Pragma("unroll")                                                   \
        for (int j = 0; j < HID; ++j) {                                     \
            const f2 wx = wr[4 * j + 0];                                    \
            const f2 wh = wr[4 * j + 1];                                    \
            const f2 bb = wr[4 * j + 2];                                    \
            const f2 w2 = wr[4 * j + 3];                                    \
            f2 hv = xv * wx + o * wh + bb;           /* v_pk_fma_f32 x2 */  \
            hv.x = __builtin_fmaxf(hv.x, 0.f);                              \
            hv.y = __builtin_fmaxf(hv.y, 0.f);       /* v_pk_max_f32 */     \
            acc += hv * w2;                          /* v_pk_fma_f32 */     \
        }                                                                   \
        o.x = fast_tanh(acc.x);                                             \
        o.y = fast_tanh(acc.y);                                             \
        R = o;                                       /* in place: x -> o */ \
    }
    ALLR(STEP)

    // ---- output: mirror half-phases ----
    __syncthreads();                                 // copy1 reads done
    if (tid < 128) { ALLR(SAVER) }
    __syncthreads();
    STAGE_OUT(0);
    __syncthreads();
    if (tid >= 128) { ALLR(SAVER) }
    __syncthreads();
    STAGE_OUT(1);
}

extern "C" void kernel_launch(void* const* d_in, const int* in_sizes, int n_in,
                              void* d_out, int out_size, void* d_ws, size_t ws_size,
                              hipStream_t stream) {
    const float* x  = (const float*)d_in[0];
    const float* W1 = (const float*)d_in[1];
    const float* b1 = (const float*)d_in[2];
    const float* W2 = (const float*)d_in[3];
    const float* b2 = (const float*)d_in[4];
    float* out = (float*)d_out;
    f2* wp2 = (f2*)d_ws;                             // 30*21*4*8 = 20160 B

    repack_w<<<1, 256, 0, stream>>>(W1, b1, W2, b2, wp2);

    const int B = 1048576;
    const int grid = B / EPB;                        // 2048 blocks
    rnn6<<<grid, 256, 0, stream>>>(x, wp2, out);
}

// Round 6
// 254.711 us; speedup vs baseline: 1.5575x; 1.4040x over previous
//
#include <hip/hip_runtime.h>

// RNN: o_t = tanh(relu([x_t, o_{t-1}] @ W1[t] + b1[t]) @ W2[t] + b2[t]), T=30.
// Round-7 design (hidden-dim packing: M=1 batch, j-pairs in v_pk_fma_f32):
//  - r6 post-mortem: full 30-step unroll = ~36KB straight-line code > 32KB I$
//    -> VALUBusy 29% at same occupancy where r3's compact loop ran 88%.
//    VGPR=48 proved the named series never sat in VGPRs either. Also the
//    duplicated-pair weights (20KB) overflowed the ~16KB scalar K$.
//  - Synthesis across rounds: r2 (M=2 packed) busy=61us but 8 waves/CU ->
//    53% util; r3 (M=1 scalar) busy=96us at 20 waves/CU -> 88% util. Batch
//    packing forces 240B/thread staged = 61KB tile = low occupancy. So pack
//    the HIDDEN dimension instead: keep r3's exact tile (31KB, 5 blocks/CU,
//    20 waves/CU, compact t-loop) and compute j in pairs:
//      h2   = pk_fma(x2, wx_pair, pk_fma(o2, wh_pair, b1_pair))
//      h2   = pk_max(h2, 0)
//      acc2 = pk_fma(h2, w2_pair, acc2)      // ~4-5 ops per 2 hidden units
//    vs ~10 scalar ops -> recurrence issue cost ~halves (96 -> ~55us busy).
//  - Broadcasts {x,x},{o,o} built once per step (2 movs). Weight layout per
//    step: 44 f2 = {wx[0..9], wh[10..19], b1[20..29], w2[30..39], b2[40],pad}
//    = 352B/step, 10.5KB total -> K$-resident; wave-uniform -> s_load.
//  - Staging/transpose phases copied verbatim from r3 (proven clean:
//    FETCH 61.5MB, WRITE 123MB, conflicts ~0.8us-class).
//  - Accumulator is split even/odd-j then added at the end; fp reassociation
//    only (same tolerance class as previous passing rounds).

#define TS  30
#define HID 20
#define THR 256
#define EPB 256              // elements per block (M=1)
#define ROW 257              // LDS row stride in floats (odd -> bank-clean)
#define WST 44               // f2 slots per timestep in repacked weights

typedef float f2 __attribute__((ext_vector_type(2)));

__device__ __forceinline__ float fast_tanh(float y) {
    // tanh(y) = 1 - 2/(exp(2y)+1); correct saturation at +/-inf.
    float e = __expf(2.0f * y);
    return 1.0f - 2.0f * __builtin_amdgcn_rcpf(e + 1.0f);
}

// wp2[t*44 + s]: s in [0,10): {W1x[2s],W1x[2s+1]}  (x-row of W1)
//               s in [10,20): {W1h[2(s-10)], W1h[2(s-10)+1]}  (h-row of W1)
//               s in [20,30): {b1[...]} pairs
//               s in [30,40): {W2[...]} pairs
//               s == 40: {b2[t], 0};  s in [41,44): zero pad.
__global__ __launch_bounds__(256) void repack_w(
        const float* __restrict__ W1, const float* __restrict__ b1,
        const float* __restrict__ W2, const float* __restrict__ b2,
        f2* __restrict__ wp2) {
    for (int i = threadIdx.x; i < TS * WST; i += 256) {
        const int t = i / WST;
        const int s = i - t * WST;
        f2 v = {0.f, 0.f};
        if (s < 10) {
            const int j = 2 * s;
            v = (f2){W1[t * 40 + j], W1[t * 40 + j + 1]};
        } else if (s < 20) {
            const int j = 2 * (s - 10);
            v = (f2){W1[t * 40 + 20 + j], W1[t * 40 + 20 + j + 1]};
        } else if (s < 30) {
            const int j = 2 * (s - 20);
            v = (f2){b1[t * 20 + j], b1[t * 20 + j + 1]};
        } else if (s < 40) {
            const int j = 2 * (s - 30);
            v = (f2){W2[t * 20 + j], W2[t * 20 + j + 1]};
        } else if (s == 40) {
            v = (f2){b2[t], 0.f};
        }
        wp2[i] = v;
    }
}

__global__ __launch_bounds__(256, 5) void rnn7(
        const float* __restrict__ x,
        const f2* __restrict__ wp2,
        float* __restrict__ out) {
    __shared__ float tile[TS * ROW];                 // 30840 B -> 5 blocks/CU
    const int tid = threadIdx.x;
    const size_t gbase = (size_t)blockIdx.x * (EPB * TS);

    // ---- coalesced float2 load + LDS transpose scatter (r3 verbatim) ----
    const float2* xg = reinterpret_cast<const float2*>(x + gbase);
#pragma unroll
    for (int i = 0; i < 15; ++i) {
        const float2 v = xg[i * THR + tid];
        const unsigned f0 = (unsigned)(i * THR + tid) * 2u;
        const unsigned e0 = (f0 * 34953u) >> 20;     // exact f/30 for f < 74898
        const unsigned t0 = f0 - e0 * 30u;
        tile[t0 * ROW + e0] = v.x;
        const unsigned f1 = f0 + 1u;
        const unsigned e1 = (f1 * 34953u) >> 20;
        const unsigned t1 = f1 - e1 * 30u;
        tile[t1 * ROW + e1] = v.y;
    }
    __syncthreads();

    // ---- recurrence: M=1, hidden units in packed j-pairs ----
    float o = 0.f;
#pragma unroll 1
    for (int t = 0; t < TS; ++t) {
        const f2* wr = wp2 + t * WST;                // wave-uniform -> s_load
        const float xv = tile[t * ROW + tid];
        const f2 x2 = {xv, xv};                      // broadcast once/step
        const f2 o2 = {o, o};
        f2 acc = {wr[40].x, 0.f};                    // b2 in one lane-half
#pragma unroll
        for (int jj = 0; jj < 10; ++jj) {
            const f2 wx = wr[jj];                    // SGPR pairs
            const f2 wh = wr[10 + jj];
            const f2 bb = wr[20 + jj];
            const f2 w2 = wr[30 + jj];
            f2 h = o2 * wh + bb;                     // v_pk_fma_f32
            h = x2 * wx + h;                         // v_pk_fma_f32
            h.x = __builtin_fmaxf(h.x, 0.f);
            h.y = __builtin_fmaxf(h.y, 0.f);         // v_pk_max_f32
            acc += h * w2;                           // v_pk_fma_f32
        }
        o = fast_tanh(acc.x + acc.y);
        tile[t * ROW + tid] = o;                     // in-place: x -> o
    }
    __syncthreads();

    // ---- LDS gather + coalesced float2 store (r3 verbatim) ----
    float2* og = reinterpret_cast<float2*>(out + gbase);
#pragma unroll
    for (int i = 0; i < 15; ++i) {
        const unsigned f0 = (unsigned)(i * THR + tid) * 2u;
        const unsigned e0 = (f0 * 34953u) >> 20;
        const unsigned t0 = f0 - e0 * 30u;
        const unsigned f1 = f0 + 1u;
        const unsigned e1 = (f1 * 34953u) >> 20;
        const unsigned t1 = f1 - e1 * 30u;
        float2 v;
        v.x = tile[t0 * ROW + e0];
        v.y = tile[t1 * ROW + e1];
        og[i * THR + tid] = v;
    }
}

extern "C" void kernel_launch(void* const* d_in, const int* in_sizes, int n_in,
                              void* d_out, int out_size, void* d_ws, size_t ws_size,
                              hipStream_t stream) {
    const float* x  = (const float*)d_in[0];
    const float* W1 = (const float*)d_in[1];
    const float* b1 = (const float*)d_in[2];
    const float* W2 = (const float*)d_in[3];
    const float* b2 = (const float*)d_in[4];
    float* out = (float*)d_out;
    f2* wp2 = (f2*)d_ws;                             // 30*44*8 = 10560 B

    repack_w<<<1, 256, 0, stream>>>(W1, b1, W2, b2, wp2);

    const int B = 1048576;
    const int grid = B / EPB;                        // 4096 blocks
    rnn7<<<grid, 256, 0, stream>>>(x, wp2, out);
}